// Round 3
// baseline (167.247 us; speedup 1.0000x reference)
//
#include <hip/hip_runtime.h>
#include <hip/hip_bf16.h>

#define GRID  2048
#define BLOCK 256
#define STRIDE (GRID * BLOCK)          // 524288 threads
#define LOG_CLAMP -100.0f

// Problem-fixed sizes (setup_inputs): specialized fast path
constexpr int NB  = 8388608;           // model_outputs / labels
constexpr int N1  = 4096 * 4096;       // w1
constexpr int N2  = 4096 * 1024;       // w2
constexpr int NB4 = NB / 4;            // 2097152 = 4 * STRIDE
constexpr int N14 = N1 / 4;            // 4194304 = 8 * STRIDE
constexpr int N24 = N2 / 4;            // 1048576 = 2 * STRIDE

struct Partials {
    float bce[GRID];
    float w1s[GRID];
    float w2s[GRID];
    unsigned int cnt[GRID];
};

__device__ __forceinline__ float wave_reduce_f(float v) {
#pragma unroll
    for (int o = 32; o > 0; o >>= 1) v += __shfl_down(v, o, 64);
    return v;
}
__device__ __forceinline__ unsigned int wave_reduce_u(unsigned int v) {
#pragma unroll
    for (int o = 32; o > 0; o >>= 1) v += __shfl_down(v, o, 64);
    return v;
}
__device__ __forceinline__ double wave_reduce_d(double v) {
#pragma unroll
    for (int o = 32; o > 0; o >>= 1) v += __shfl_down(v, o, 64);
    return v;
}

__device__ __forceinline__ void block_reduce_store(
    float bce, float s1, float s2, unsigned int cnt, Partials* ws)
{
    float rb = wave_reduce_f(bce);
    float r1 = wave_reduce_f(s1);
    float r2 = wave_reduce_f(s2);
    unsigned int rc = wave_reduce_u(cnt);

    __shared__ float sb[BLOCK / 64], s1s[BLOCK / 64], s2s[BLOCK / 64];
    __shared__ unsigned int scs[BLOCK / 64];
    const int wave = threadIdx.x >> 6;
    const int lane = threadIdx.x & 63;
    if (lane == 0) { sb[wave] = rb; s1s[wave] = r1; s2s[wave] = r2; scs[wave] = rc; }
    __syncthreads();
    if (threadIdx.x == 0) {
        float tb = 0.0f, t1 = 0.0f, t2 = 0.0f;
        unsigned int tc = 0;
#pragma unroll
        for (int w = 0; w < BLOCK / 64; ++w) { tb += sb[w]; t1 += s1s[w]; t2 += s2s[w]; tc += scs[w]; }
        ws->bce[blockIdx.x] = tb;
        ws->w1s[blockIdx.x] = t1;
        ws->w2s[blockIdx.x] = t2;
        ws->cnt[blockIdx.x] = tc;
    }
}

// BCE term + accuracy count for one scalar pair
#define BCE_COMP(px, yx)                                            \
    {                                                               \
        float lp  = fmaxf(__logf(px), LOG_CLAMP);                   \
        float l1  = fmaxf(__logf(1.0f - (px)), LOG_CLAMP);          \
        bce += l1 + (yx) * (lp - l1);                               \
        cnt += (fabsf((px) - (yx)) < 0.5f) ? 1u : 0u;               \
    }

// ---- specialized: compile-time trip counts (4/8/2), all 14 loads in flight ----
__global__ __launch_bounds__(BLOCK) void reduce_fixed(
    const float4* __restrict__ p4, const float4* __restrict__ y4,
    const float4* __restrict__ w14, const float4* __restrict__ w24,
    Partials* __restrict__ ws)
{
    const int tid = blockIdx.x * BLOCK + threadIdx.x;

    float4 pv[4], yv[4], av[8], bv[2];
#pragma unroll
    for (int k = 0; k < 4; ++k) pv[k] = p4[tid + k * STRIDE];
#pragma unroll
    for (int k = 0; k < 4; ++k) yv[k] = y4[tid + k * STRIDE];
#pragma unroll
    for (int k = 0; k < 8; ++k) av[k] = w14[tid + k * STRIDE];
#pragma unroll
    for (int k = 0; k < 2; ++k) bv[k] = w24[tid + k * STRIDE];

    float bce = 0.0f, s1 = 0.0f, s2 = 0.0f;
    unsigned int cnt = 0;

#pragma unroll
    for (int k = 0; k < 4; ++k) {
        BCE_COMP(pv[k].x, yv[k].x)
        BCE_COMP(pv[k].y, yv[k].y)
        BCE_COMP(pv[k].z, yv[k].z)
        BCE_COMP(pv[k].w, yv[k].w)
    }
#pragma unroll
    for (int k = 0; k < 8; ++k)
        s1 += av[k].x * av[k].x + av[k].y * av[k].y + av[k].z * av[k].z + av[k].w * av[k].w;
#pragma unroll
    for (int k = 0; k < 2; ++k)
        s2 += bv[k].x * bv[k].x + bv[k].y * bv[k].y + bv[k].z * bv[k].z + bv[k].w * bv[k].w;

    block_reduce_store(bce, s1, s2, cnt, ws);
}

// ---- generic fallback: grid-stride (only used if sizes differ) ----
__global__ __launch_bounds__(BLOCK) void reduce_generic(
    const float* __restrict__ p, const float* __restrict__ y,
    const float* __restrict__ w1, const float* __restrict__ w2,
    int nB4, int n14, int n24, Partials* __restrict__ ws)
{
    const float4* __restrict__ p4  = (const float4*)p;
    const float4* __restrict__ y4  = (const float4*)y;
    const float4* __restrict__ w14 = (const float4*)w1;
    const float4* __restrict__ w24 = (const float4*)w2;

    const int tid = blockIdx.x * BLOCK + threadIdx.x;
    float bce = 0.0f, s1 = 0.0f, s2 = 0.0f;
    unsigned int cnt = 0;

    for (int i = tid; i < nB4; i += STRIDE) {
        float4 pv = p4[i];
        float4 yv = y4[i];
        BCE_COMP(pv.x, yv.x)
        BCE_COMP(pv.y, yv.y)
        BCE_COMP(pv.z, yv.z)
        BCE_COMP(pv.w, yv.w)
    }
    for (int i = tid; i < n14; i += STRIDE) {
        float4 v = w14[i];
        s1 += v.x * v.x + v.y * v.y + v.z * v.z + v.w * v.w;
    }
    for (int i = tid; i < n24; i += STRIDE) {
        float4 v = w24[i];
        s2 += v.x * v.x + v.y * v.y + v.z * v.z + v.w * v.w;
    }
    block_reduce_store(bce, s1, s2, cnt, ws);
}

__global__ __launch_bounds__(BLOCK) void finalize_kernel(
    const Partials* __restrict__ ws, float* __restrict__ out, int nB)
{
    double bce = 0.0, s1 = 0.0, s2 = 0.0;
    unsigned int cnt = 0;
    for (int i = threadIdx.x; i < GRID; i += BLOCK) {
        bce += (double)ws->bce[i];
        s1  += (double)ws->w1s[i];
        s2  += (double)ws->w2s[i];
        cnt += ws->cnt[i];
    }
    double rb = wave_reduce_d(bce);
    double r1 = wave_reduce_d(s1);
    double r2 = wave_reduce_d(s2);
    unsigned int rc = wave_reduce_u(cnt);

    __shared__ double sb[BLOCK / 64], s1s[BLOCK / 64], s2s[BLOCK / 64];
    __shared__ unsigned int scs[BLOCK / 64];
    const int wave = threadIdx.x >> 6;
    const int lane = threadIdx.x & 63;
    if (lane == 0) { sb[wave] = rb; s1s[wave] = r1; s2s[wave] = r2; scs[wave] = rc; }
    __syncthreads();
    if (threadIdx.x == 0) {
        double tb = 0.0, t1 = 0.0, t2 = 0.0;
        unsigned int tc = 0;
#pragma unroll
        for (int w = 0; w < BLOCK / 64; ++w) { tb += sb[w]; t1 += s1s[w]; t2 += s2s[w]; tc += scs[w]; }
        const double invB = 1.0 / (double)nB;
        double result = -tb * invB + (0.01 * t1 + 0.001 * t2) * (0.5 * invB);
        out[0] = (float)result;
        out[1] = (float)tc;
    }
}

extern "C" void kernel_launch(void* const* d_in, const int* in_sizes, int n_in,
                              void* d_out, int out_size, void* d_ws, size_t ws_size,
                              hipStream_t stream) {
    const float* p  = (const float*)d_in[0];   // model_outputs
    const float* y  = (const float*)d_in[1];   // labels
    const float* w1 = (const float*)d_in[2];   // 4096x4096
    const float* w2 = (const float*)d_in[3];   // 4096x1024
    const int nB = in_sizes[0];
    const int n1 = in_sizes[2];
    const int n2 = in_sizes[3];

    Partials* ws = (Partials*)d_ws;
    float* out = (float*)d_out;

    if (nB == NB && n1 == N1 && n2 == N2 && in_sizes[1] == NB) {
        reduce_fixed<<<GRID, BLOCK, 0, stream>>>(
            (const float4*)p, (const float4*)y, (const float4*)w1, (const float4*)w2, ws);
    } else {
        reduce_generic<<<GRID, BLOCK, 0, stream>>>(p, y, w1, w2, nB / 4, n1 / 4, n2 / 4, ws);
    }
    finalize_kernel<<<1, BLOCK, 0, stream>>>(ws, out, nB);
}